// Round 9
// baseline (179.135 us; speedup 1.0000x reference)
//
#include <hip/hip_runtime.h>
#include <hip/hip_bf16.h>

// Problem: B=64, ATT_SIZE(S)=1024, RNN_SIZE(D)=2048, ATT_HID(H)=512
// att_h = h @ W^T + b            [64, 512]
// scores= tanh(p_att + att_h) @ w_alpha   [64, 1024]  (b_alpha cancels in softmax)
// weight= softmax(scores, s)     [64, 1024]
// out   = weight @ att_feats     [64, 2048]
//
// K1 h2att -> K2 fused at sc=8 (512 blocks = 2/CU, the measured-optimal
// stream shape: 2048blk=146us, 512blk=126.8us, 256blk=132us) with
// IN-KERNEL last-block merge (device-scope atomic counter + threadfence;
// saves the merge launch + po HBM round-trip).

#define B 64
#define S 1024
#define D 2048
#define H 512

typedef float f32x4 __attribute__((ext_vector_type(4)));
typedef float f32x2 __attribute__((ext_vector_type(2)));

__device__ __forceinline__ f32x4 nt_load4(const f32x4* p) {
  return __builtin_nontemporal_load(p);
}

// fast tanh: 1 - 2/(e^{2x}+1). Safe at +/-inf (e=inf -> 1; e=0 -> -1).
__device__ __forceinline__ float fast_tanh(float x) {
  float e = __expf(2.f * x);
  return 1.f - 2.f * __builtin_amdgcn_rcpf(e + 1.f);
}

// ---------------- K1: att_h = h @ W^T + bias ----------------
// Wave computes a 4b x 4j tile. 512 blocks x 256 threads.
__global__ __launch_bounds__(256) void k_h2att(
    const f32x4* __restrict__ h4, const f32x4* __restrict__ W4,
    const float* __restrict__ bias, float* __restrict__ att_h) {
  const int tid = threadIdx.x, lane = tid & 63, wave = tid >> 6;
  const int tile = blockIdx.x * 4 + wave;  // [0, 2048)
  const int b0 = (tile >> 7) << 2;         // [0, 64) step 4
  const int j0 = (tile & 127) << 2;        // [0, 512) step 4
  float acc[4][4] = {};
#pragma unroll
  for (int i = 0; i < 8; ++i) {
    const int idx = lane + i * 64;  // [0, 512) f32x4 within a 2048-f row
    f32x4 hv[4], wv[4];
#pragma unroll
    for (int x = 0; x < 4; ++x) hv[x] = h4[(size_t)(b0 + x) * 512 + idx];
#pragma unroll
    for (int x = 0; x < 4; ++x) wv[x] = W4[(size_t)(j0 + x) * 512 + idx];
#pragma unroll
    for (int bb = 0; bb < 4; ++bb)
#pragma unroll
      for (int jj = 0; jj < 4; ++jj)
        acc[bb][jj] += hv[bb].x * wv[jj].x + hv[bb].y * wv[jj].y +
                       hv[bb].z * wv[jj].z + hv[bb].w * wv[jj].w;
  }
#pragma unroll
  for (int bb = 0; bb < 4; ++bb)
#pragma unroll
    for (int jj = 0; jj < 4; ++jj) {
      float a = acc[bb][jj];
#pragma unroll
      for (int off = 32; off; off >>= 1) a += __shfl_xor(a, off, 64);
      if (lane == bb * 4 + jj)
        att_h[(b0 + bb) * H + j0 + jj] = a + bias[j0 + jj];
    }
}

// ---------------- K2: fused scores + chunk softmax + partial wsum + merge
// grid = B*sc = 512 blocks (2/CU); bx -> (b = bx/sc, c = bx%sc), rows
// [c*spc, c*spc+spc), spc=128. Phase 1: 4 score rows per wave-iteration
// (8 indep loads in flight) -> slds. Phase 2: chunk-local max m_c,
// e_i = exp(s_i - m_c) -> wlds; meta[bx] = (m_c, l_c). Phase 3: full-D
// partial weighted sum -> po[bx] (normal stores, stays L2-resident).
// Phase 4: last finishing block of each b merges all sc partials.
__global__ __launch_bounds__(256) void k_fused(
    const f32x4* __restrict__ p4, const f32x4* __restrict__ f4,
    const f32x4* __restrict__ ah4, const f32x4* __restrict__ wa4,
    f32x4* __restrict__ po, float2* __restrict__ meta, int* __restrict__ cnt,
    f32x2* __restrict__ out2, int sc, int spc) {
  __shared__ float slds[S];
  __shared__ float wlds[S];
  __shared__ float redm[4], redl[4];
  __shared__ int is_last;
  const int tid = threadIdx.x, lane = tid & 63, wave = tid >> 6;
  const int bx = blockIdx.x;
  const int b = bx / sc, c = bx - b * sc;
  const int s0 = c * spc;

  // ---- phase 1: scores for this chunk ----
  const f32x4* pbase = p4 + ((size_t)b * S + s0) * 128;
  const f32x4 av0 = ah4[b * 128 + lane], av1 = ah4[b * 128 + 64 + lane];
  const f32x4 wv0 = wa4[lane], wv1 = wa4[64 + lane];
  const int rpw = spc >> 2;    // rows per wave (32 at sc=8)
  const int iters = rpw >> 2;  // 4-row groups per wave
  for (int it = 0; it < iters; ++it) {
    const int sl0 = wave * rpw + it * 4;
    float acc[4];
#pragma unroll
    for (int r = 0; r < 4; ++r) {
      const f32x4* p = pbase + (size_t)(sl0 + r) * 128;
      f32x4 p0 = nt_load4(p + lane), p1 = nt_load4(p + 64 + lane);
      acc[r] = fast_tanh(p0.x + av0.x) * wv0.x +
               fast_tanh(p0.y + av0.y) * wv0.y +
               fast_tanh(p0.z + av0.z) * wv0.z +
               fast_tanh(p0.w + av0.w) * wv0.w +
               fast_tanh(p1.x + av1.x) * wv1.x +
               fast_tanh(p1.y + av1.y) * wv1.y +
               fast_tanh(p1.z + av1.z) * wv1.z +
               fast_tanh(p1.w + av1.w) * wv1.w;
    }
#pragma unroll
    for (int r = 0; r < 4; ++r)
#pragma unroll
      for (int off = 32; off; off >>= 1) acc[r] += __shfl_xor(acc[r], off, 64);
    if (lane == 0) {
      f32x4 o = {acc[0], acc[1], acc[2], acc[3]};
      ((f32x4*)slds)[sl0 >> 2] = o;
    }
  }
  __syncthreads();

  // ---- phase 2: chunk-local softmax weights ----
  float m = -INFINITY;
  for (int i = tid; i < spc; i += 256) m = fmaxf(m, slds[i]);
#pragma unroll
  for (int off = 32; off; off >>= 1) m = fmaxf(m, __shfl_xor(m, off, 64));
  if (lane == 0) redm[wave] = m;
  __syncthreads();
  const float M = fmaxf(fmaxf(redm[0], redm[1]), fmaxf(redm[2], redm[3]));
  float l = 0.f;
  for (int i = tid; i < spc; i += 256) {
    float e = __expf(slds[i] - M);
    wlds[i] = e;
    l += e;
  }
#pragma unroll
  for (int off = 32; off; off >>= 1) l += __shfl_xor(l, off, 64);
  if (lane == 0) redl[wave] = l;
  __syncthreads();
  if (tid == 0)
    meta[bx] = make_float2(M, redl[0] + redl[1] + redl[2] + redl[3]);

  // ---- phase 3: partial weighted sum over this chunk, full D ----
  const f32x4* frow = f4 + ((size_t)b * S + s0) * 512 + tid;
  f32x4 acc0 = {0.f, 0.f, 0.f, 0.f}, acc1 = {0.f, 0.f, 0.f, 0.f};
#pragma unroll 8
  for (int i = 0; i < spc; ++i) {
    const float w = wlds[i];
    f32x4 v0 = nt_load4(frow + (size_t)i * 512);
    f32x4 v1 = nt_load4(frow + (size_t)i * 512 + 256);
    acc0.x += w * v0.x;
    acc0.y += w * v0.y;
    acc0.z += w * v0.z;
    acc0.w += w * v0.w;
    acc1.x += w * v1.x;
    acc1.y += w * v1.y;
    acc1.z += w * v1.z;
    acc1.w += w * v1.w;
  }
  po[(size_t)bx * 512 + tid] = acc0;          // normal stores -> L2
  po[(size_t)bx * 512 + tid + 256] = acc1;

  // ---- phase 4: last block of this b merges ----
  __syncthreads();  // all po/meta stores of this block issued
  if (tid == 0) {
    __threadfence();  // release: make po/meta visible device-wide
    int old = atomicAdd(&cnt[b], 1);
    is_last = (old == sc - 1) ? 1 : 0;
  }
  __syncthreads();
  if (!is_last) return;
  __threadfence();  // acquire: see all other blocks' po/meta

  float Mg = -INFINITY;
  for (int cc = 0; cc < sc; ++cc) Mg = fmaxf(Mg, meta[b * sc + cc].x);
  float Lg = 0.f;
  for (int cc = 0; cc < sc; ++cc) {
    float2 mc = meta[b * sc + cc];
    Lg += mc.y * __expf(mc.x - Mg);
  }
  const float invL = 1.f / Lg;
  const f32x2* po2 = (const f32x2*)po;
#pragma unroll
  for (int q = 0; q < 4; ++q) {
    const int off = q * 256 + tid;  // f32x2 index within b's 1024
    f32x2 acc = {0.f, 0.f};
    for (int cc = 0; cc < sc; ++cc) {
      const float w = __expf(meta[b * sc + cc].x - Mg) * invL;
      f32x2 v = po2[((size_t)(b * sc + cc)) * 1024 + off];
      acc.x += w * v.x;
      acc.y += w * v.y;
    }
    out2[(size_t)b * 1024 + off] = acc;
  }
}

extern "C" void kernel_launch(void* const* d_in, const int* in_sizes, int n_in,
                              void* d_out, int out_size, void* d_ws,
                              size_t ws_size, hipStream_t stream) {
  const float* h = (const float*)d_in[0];
  const float* att_feats = (const float*)d_in[1];
  const float* p_att = (const float*)d_in[2];
  const float* W = (const float*)d_in[3];
  const float* bh = (const float*)d_in[4];
  const float* wa = (const float*)d_in[5];
  // d_in[6] = b_alpha (cancels in softmax)
  float* out = (float*)d_out;
  float* ws = (float*)d_ws;

  float* att_h = ws;                       // 32768 floats
  float2* meta = (float2*)(ws + 32768);    // pad 4096 floats
  int* cnt = (int*)(ws + 32768 + 4096);    // pad 1024 floats (B ints used)
  float* po = ws + 32768 + 4096 + 1024;    // B*sc*2048 floats (16B-aligned)

  int sc = 8;  // 512 blocks = 2/CU: measured-optimal stream shape
  while (sc > 1 &&
         ws_size < (32768ull + 4096ull + 1024ull + (size_t)B * sc * D) * 4ull)
    sc >>= 1;
  const int spc = S / sc;

  k_h2att<<<(B / 4) * (H / 4) / 4, 256, 0, stream>>>(
      (const f32x4*)h, (const f32x4*)W, bh, att_h);
  hipMemsetAsync(cnt, 0, B * sizeof(int), stream);  // zero merge counters
  k_fused<<<B * sc, 256, 0, stream>>>(
      (const f32x4*)p_att, (const f32x4*)att_feats, (const f32x4*)att_h,
      (const f32x4*)wa, (f32x4*)po, meta, cnt, (f32x2*)out, sc, spc);
}

// Round 10
// 145.652 us; speedup vs baseline: 1.2299x; 1.2299x over previous
//
#include <hip/hip_runtime.h>
#include <hip/hip_bf16.h>

// Problem: B=64, ATT_SIZE(S)=1024, RNN_SIZE(D)=2048, ATT_HID(H)=512
// att_h = h @ W^T + b            [64, 512]
// scores= tanh(p_att + att_h) @ w_alpha   [64, 1024]  (b_alpha cancels in softmax)
// weight= softmax(scores, s)     [64, 1024]
// out   = weight @ att_feats     [64, 2048]
//
// r10 = r7 structure (best measured: 126.8us) with ONE change: plain loads
// instead of nontemporal loads (A/B the nt cache-bypass flag).
// K1 h2att -> K2 fused at sc=8 (512 blocks = 2/CU, measured-optimal
// stream shape: 2048blk=146, 512blk=126.8, 256blk=132) -> K3 merge.
// r9 lesson: NO cross-XCD atomic merge inside the streaming kernel (+52us).

#define B 64
#define S 1024
#define D 2048
#define H 512

typedef float f32x4 __attribute__((ext_vector_type(4)));
typedef float f32x2 __attribute__((ext_vector_type(2)));

// fast tanh: 1 - 2/(e^{2x}+1). Safe at +/-inf (e=inf -> 1; e=0 -> -1).
__device__ __forceinline__ float fast_tanh(float x) {
  float e = __expf(2.f * x);
  return 1.f - 2.f * __builtin_amdgcn_rcpf(e + 1.f);
}

// ---------------- K1: att_h = h @ W^T + bias ----------------
// Wave computes a 4b x 4j tile. 512 blocks x 256 threads. (~4.5 us)
__global__ __launch_bounds__(256) void k_h2att(
    const f32x4* __restrict__ h4, const f32x4* __restrict__ W4,
    const float* __restrict__ bias, float* __restrict__ att_h) {
  const int tid = threadIdx.x, lane = tid & 63, wave = tid >> 6;
  const int tile = blockIdx.x * 4 + wave;  // [0, 2048)
  const int b0 = (tile >> 7) << 2;         // [0, 64) step 4
  const int j0 = (tile & 127) << 2;        // [0, 512) step 4
  float acc[4][4] = {};
#pragma unroll
  for (int i = 0; i < 8; ++i) {
    const int idx = lane + i * 64;  // [0, 512) f32x4 within a 2048-f row
    f32x4 hv[4], wv[4];
#pragma unroll
    for (int x = 0; x < 4; ++x) hv[x] = h4[(size_t)(b0 + x) * 512 + idx];
#pragma unroll
    for (int x = 0; x < 4; ++x) wv[x] = W4[(size_t)(j0 + x) * 512 + idx];
#pragma unroll
    for (int bb = 0; bb < 4; ++bb)
#pragma unroll
      for (int jj = 0; jj < 4; ++jj)
        acc[bb][jj] += hv[bb].x * wv[jj].x + hv[bb].y * wv[jj].y +
                       hv[bb].z * wv[jj].z + hv[bb].w * wv[jj].w;
  }
#pragma unroll
  for (int bb = 0; bb < 4; ++bb)
#pragma unroll
    for (int jj = 0; jj < 4; ++jj) {
      float a = acc[bb][jj];
#pragma unroll
      for (int off = 32; off; off >>= 1) a += __shfl_xor(a, off, 64);
      if (lane == bb * 4 + jj)
        att_h[(b0 + bb) * H + j0 + jj] = a + bias[j0 + jj];
    }
}

// ---------------- K2: fused scores + chunk softmax + partial wsum -------
// grid = B*sc = 512 blocks (2/CU); bx -> (b = bx/sc, c = bx%sc), rows
// [c*spc, c*spc+spc), spc=128. Phase 1: 4 score rows per wave-iteration
// (8 indep loads in flight) -> slds. Phase 2: chunk-local max m_c,
// e_i = exp(s_i - m_c) -> wlds; meta[bx] = (m_c, l_c). Phase 3: full-D
// partial weighted sum (the r5-proven 95%-BW stream shape).
__global__ __launch_bounds__(256) void k_fused(
    const f32x4* __restrict__ p4, const f32x4* __restrict__ f4,
    const f32x4* __restrict__ ah4, const f32x4* __restrict__ wa4,
    f32x4* __restrict__ po, float2* __restrict__ meta, int sc, int spc) {
  __shared__ float slds[S];
  __shared__ float wlds[S];
  __shared__ float redm[4], redl[4];
  const int tid = threadIdx.x, lane = tid & 63, wave = tid >> 6;
  const int bx = blockIdx.x;
  const int b = bx / sc, c = bx - b * sc;
  const int s0 = c * spc;

  // ---- phase 1: scores for this chunk ----
  const f32x4* pbase = p4 + ((size_t)b * S + s0) * 128;
  const f32x4 av0 = ah4[b * 128 + lane], av1 = ah4[b * 128 + 64 + lane];
  const f32x4 wv0 = wa4[lane], wv1 = wa4[64 + lane];
  const int rpw = spc >> 2;    // rows per wave (32 at sc=8)
  const int iters = rpw >> 2;  // 4-row groups per wave
  for (int it = 0; it < iters; ++it) {
    const int sl0 = wave * rpw + it * 4;
    float acc[4];
#pragma unroll
    for (int r = 0; r < 4; ++r) {
      const f32x4* p = pbase + (size_t)(sl0 + r) * 128;
      f32x4 p0 = p[lane], p1 = p[64 + lane];
      acc[r] = fast_tanh(p0.x + av0.x) * wv0.x +
               fast_tanh(p0.y + av0.y) * wv0.y +
               fast_tanh(p0.z + av0.z) * wv0.z +
               fast_tanh(p0.w + av0.w) * wv0.w +
               fast_tanh(p1.x + av1.x) * wv1.x +
               fast_tanh(p1.y + av1.y) * wv1.y +
               fast_tanh(p1.z + av1.z) * wv1.z +
               fast_tanh(p1.w + av1.w) * wv1.w;
    }
#pragma unroll
    for (int r = 0; r < 4; ++r)
#pragma unroll
      for (int off = 32; off; off >>= 1) acc[r] += __shfl_xor(acc[r], off, 64);
    if (lane == 0) {
      f32x4 o = {acc[0], acc[1], acc[2], acc[3]};
      ((f32x4*)slds)[sl0 >> 2] = o;
    }
  }
  __syncthreads();

  // ---- phase 2: chunk-local softmax weights ----
  float m = -INFINITY;
  for (int i = tid; i < spc; i += 256) m = fmaxf(m, slds[i]);
#pragma unroll
  for (int off = 32; off; off >>= 1) m = fmaxf(m, __shfl_xor(m, off, 64));
  if (lane == 0) redm[wave] = m;
  __syncthreads();
  const float M = fmaxf(fmaxf(redm[0], redm[1]), fmaxf(redm[2], redm[3]));
  float l = 0.f;
  for (int i = tid; i < spc; i += 256) {
    float e = __expf(slds[i] - M);
    wlds[i] = e;
    l += e;
  }
#pragma unroll
  for (int off = 32; off; off >>= 1) l += __shfl_xor(l, off, 64);
  if (lane == 0) redl[wave] = l;
  __syncthreads();
  if (tid == 0)
    meta[bx] = make_float2(M, redl[0] + redl[1] + redl[2] + redl[3]);

  // ---- phase 3: partial weighted sum over this chunk, full D ----
  const f32x4* frow = f4 + ((size_t)b * S + s0) * 512 + tid;
  f32x4 acc0 = {0.f, 0.f, 0.f, 0.f}, acc1 = {0.f, 0.f, 0.f, 0.f};
#pragma unroll 8
  for (int i = 0; i < spc; ++i) {
    const float w = wlds[i];
    f32x4 v0 = frow[(size_t)i * 512];
    f32x4 v1 = frow[(size_t)i * 512 + 256];
    acc0.x += w * v0.x;
    acc0.y += w * v0.y;
    acc0.z += w * v0.z;
    acc0.w += w * v0.w;
    acc1.x += w * v1.x;
    acc1.y += w * v1.y;
    acc1.z += w * v1.z;
    acc1.w += w * v1.w;
  }
  po[(size_t)bx * 512 + tid] = acc0;
  po[(size_t)bx * 512 + tid + 256] = acc1;
}

// ---------------- K3: merge partials with flash rescale ----------------
// 256 blocks: (b = bx>>2, q = bx&3); thread owns f32x2 index q*256+tid of
// b's 1024. out[b,:] = sum_c e^{m_c-M} o_c / (sum_c l_c e^{m_c-M}).
__global__ __launch_bounds__(256) void k_merge(
    const f32x2* __restrict__ po2, const float2* __restrict__ meta,
    f32x2* __restrict__ out2, int sc) {
  const int bx = blockIdx.x;
  const int b = bx >> 2, q = bx & 3;
  const int tid = threadIdx.x;
  float M = -INFINITY;
  for (int c = 0; c < sc; ++c) M = fmaxf(M, meta[b * sc + c].x);
  float L = 0.f;
  for (int c = 0; c < sc; ++c) {
    float2 mc = meta[b * sc + c];
    L += mc.y * __expf(mc.x - M);
  }
  const float invL = 1.f / L;
  const int off = q * 256 + tid;  // f32x2 index within b's 1024
  f32x2 acc = {0.f, 0.f};
  for (int c = 0; c < sc; ++c) {
    const float w = __expf(meta[b * sc + c].x - M) * invL;
    f32x2 v = po2[((size_t)(b * sc + c)) * 1024 + off];
    acc.x += w * v.x;
    acc.y += w * v.y;
  }
  out2[(size_t)b * 1024 + off] = acc;
}

extern "C" void kernel_launch(void* const* d_in, const int* in_sizes, int n_in,
                              void* d_out, int out_size, void* d_ws,
                              size_t ws_size, hipStream_t stream) {
  const float* h = (const float*)d_in[0];
  const float* att_feats = (const float*)d_in[1];
  const float* p_att = (const float*)d_in[2];
  const float* W = (const float*)d_in[3];
  const float* bh = (const float*)d_in[4];
  const float* wa = (const float*)d_in[5];
  // d_in[6] = b_alpha (cancels in softmax)
  float* out = (float*)d_out;
  float* ws = (float*)d_ws;

  float* att_h = ws;                     // 32768 floats
  float2* meta = (float2*)(ws + 32768);  // pad 4096 floats
  float* po = ws + 32768 + 4096;         // B*sc*2048 floats (16B-aligned)

  int sc = 8;  // 512 blocks = 2/CU: measured-optimal stream shape
  while (sc > 1 &&
         ws_size < (32768ull + 4096ull + (size_t)B * sc * D) * 4ull)
    sc >>= 1;
  const int spc = S / sc;

  k_h2att<<<(B / 4) * (H / 4) / 4, 256, 0, stream>>>(
      (const f32x4*)h, (const f32x4*)W, bh, att_h);
  k_fused<<<B * sc, 256, 0, stream>>>(
      (const f32x4*)p_att, (const f32x4*)att_feats, (const f32x4*)att_h,
      (const f32x4*)wa, (f32x4*)po, meta, sc, spc);
  k_merge<<<B * 4, 256, 0, stream>>>((const f32x2*)po, meta, (f32x2*)out, sc);
}

// Round 11
// 128.684 us; speedup vs baseline: 1.3921x; 1.1319x over previous
//
#include <hip/hip_runtime.h>
#include <hip/hip_bf16.h>

// Problem: B=64, ATT_SIZE(S)=1024, RNN_SIZE(D)=2048, ATT_HID(H)=512
// att_h = h @ W^T + b            [64, 512]
// scores= tanh(p_att + att_h) @ w_alpha   [64, 1024]  (b_alpha cancels in softmax)
// weight= softmax(scores, s)     [64, 1024]
// out   = weight @ att_feats     [64, 2048]
//
// r11 = r7 structure (best: 126.8us, nt loads REQUIRED: removing them cost
// +19us in r10) with ONE change: k_fused at 512 threads/block (8 waves),
// same 512-block grid -> 16 waves/CU (2x memory parallelism, same stream
// count/shape). Stream ladder so far: 256blk=132, 512blk=126.8, 2048blk=146.
// r9 lesson: NO cross-XCD atomic merge inside the streaming kernel (+52us).

#define B 64
#define S 1024
#define D 2048
#define H 512

typedef float f32x4 __attribute__((ext_vector_type(4)));
typedef float f32x2 __attribute__((ext_vector_type(2)));

__device__ __forceinline__ f32x4 nt_load4(const f32x4* p) {
  return __builtin_nontemporal_load(p);
}

// fast tanh: 1 - 2/(e^{2x}+1). Safe at +/-inf (e=inf -> 1; e=0 -> -1).
__device__ __forceinline__ float fast_tanh(float x) {
  float e = __expf(2.f * x);
  return 1.f - 2.f * __builtin_amdgcn_rcpf(e + 1.f);
}

// ---------------- K1: att_h = h @ W^T + bias ----------------
// Wave computes a 4b x 4j tile. 512 blocks x 256 threads. (~4.5 us)
__global__ __launch_bounds__(256) void k_h2att(
    const f32x4* __restrict__ h4, const f32x4* __restrict__ W4,
    const float* __restrict__ bias, float* __restrict__ att_h) {
  const int tid = threadIdx.x, lane = tid & 63, wave = tid >> 6;
  const int tile = blockIdx.x * 4 + wave;  // [0, 2048)
  const int b0 = (tile >> 7) << 2;         // [0, 64) step 4
  const int j0 = (tile & 127) << 2;        // [0, 512) step 4
  float acc[4][4] = {};
#pragma unroll
  for (int i = 0; i < 8; ++i) {
    const int idx = lane + i * 64;  // [0, 512) f32x4 within a 2048-f row
    f32x4 hv[4], wv[4];
#pragma unroll
    for (int x = 0; x < 4; ++x) hv[x] = h4[(size_t)(b0 + x) * 512 + idx];
#pragma unroll
    for (int x = 0; x < 4; ++x) wv[x] = W4[(size_t)(j0 + x) * 512 + idx];
#pragma unroll
    for (int bb = 0; bb < 4; ++bb)
#pragma unroll
      for (int jj = 0; jj < 4; ++jj)
        acc[bb][jj] += hv[bb].x * wv[jj].x + hv[bb].y * wv[jj].y +
                       hv[bb].z * wv[jj].z + hv[bb].w * wv[jj].w;
  }
#pragma unroll
  for (int bb = 0; bb < 4; ++bb)
#pragma unroll
    for (int jj = 0; jj < 4; ++jj) {
      float a = acc[bb][jj];
#pragma unroll
      for (int off = 32; off; off >>= 1) a += __shfl_xor(a, off, 64);
      if (lane == bb * 4 + jj)
        att_h[(b0 + bb) * H + j0 + jj] = a + bias[j0 + jj];
    }
}

// ---------------- K2: fused scores + chunk softmax + partial wsum -------
// grid = B*sc = 512 blocks x 512 threads (8 waves; 2 blocks/CU = 16
// waves/CU); bx -> (b = bx/sc, c = bx%sc), rows [c*spc, c*spc+spc),
// spc=128. Phase 1: 4 score rows per wave-iteration (8 indep nt loads in
// flight) -> slds. Phase 2: chunk-local max m_c, e_i = exp(s_i-m_c) ->
// wlds; meta[bx] = (m_c, l_c). Phase 3: one f32x4 of D per thread (512
// threads = full 8KB row), nt-streamed, unroll 8.
__global__ __launch_bounds__(512) void k_fused(
    const f32x4* __restrict__ p4, const f32x4* __restrict__ f4,
    const f32x4* __restrict__ ah4, const f32x4* __restrict__ wa4,
    f32x4* __restrict__ po, float2* __restrict__ meta, int sc, int spc) {
  __shared__ float slds[S];
  __shared__ float wlds[S];
  __shared__ float redm[8], redl[8];
  const int tid = threadIdx.x, lane = tid & 63, wave = tid >> 6;  // 8 waves
  const int bx = blockIdx.x;
  const int b = bx / sc, c = bx - b * sc;
  const int s0 = c * spc;

  // ---- phase 1: scores for this chunk ----
  const f32x4* pbase = p4 + ((size_t)b * S + s0) * 128;
  const f32x4 av0 = ah4[b * 128 + lane], av1 = ah4[b * 128 + 64 + lane];
  const f32x4 wv0 = wa4[lane], wv1 = wa4[64 + lane];
  const int rpw = spc >> 3;    // rows per wave (16 at sc=8)
  const int iters = rpw >> 2;  // 4-row groups per wave (4)
  for (int it = 0; it < iters; ++it) {
    const int sl0 = wave * rpw + it * 4;
    float acc[4];
#pragma unroll
    for (int r = 0; r < 4; ++r) {
      const f32x4* p = pbase + (size_t)(sl0 + r) * 128;
      f32x4 p0 = nt_load4(p + lane), p1 = nt_load4(p + 64 + lane);
      acc[r] = fast_tanh(p0.x + av0.x) * wv0.x +
               fast_tanh(p0.y + av0.y) * wv0.y +
               fast_tanh(p0.z + av0.z) * wv0.z +
               fast_tanh(p0.w + av0.w) * wv0.w +
               fast_tanh(p1.x + av1.x) * wv1.x +
               fast_tanh(p1.y + av1.y) * wv1.y +
               fast_tanh(p1.z + av1.z) * wv1.z +
               fast_tanh(p1.w + av1.w) * wv1.w;
    }
#pragma unroll
    for (int r = 0; r < 4; ++r)
#pragma unroll
      for (int off = 32; off; off >>= 1) acc[r] += __shfl_xor(acc[r], off, 64);
    if (lane == 0) {
      f32x4 o = {acc[0], acc[1], acc[2], acc[3]};
      ((f32x4*)slds)[sl0 >> 2] = o;
    }
  }
  __syncthreads();

  // ---- phase 2: chunk-local softmax weights ----
  float m = -INFINITY;
  for (int i = tid; i < spc; i += 512) m = fmaxf(m, slds[i]);
#pragma unroll
  for (int off = 32; off; off >>= 1) m = fmaxf(m, __shfl_xor(m, off, 64));
  if (lane == 0) redm[wave] = m;
  __syncthreads();
  float M = redm[0];
#pragma unroll
  for (int w = 1; w < 8; ++w) M = fmaxf(M, redm[w]);
  float l = 0.f;
  for (int i = tid; i < spc; i += 512) {
    float e = __expf(slds[i] - M);
    wlds[i] = e;
    l += e;
  }
#pragma unroll
  for (int off = 32; off; off >>= 1) l += __shfl_xor(l, off, 64);
  if (lane == 0) redl[wave] = l;
  __syncthreads();
  if (tid == 0) {
    float L = 0.f;
#pragma unroll
    for (int w = 1; w < 8; ++w) L += redl[w];
    meta[bx] = make_float2(M, L + redl[0]);
  }

  // ---- phase 3: partial weighted sum; one f32x4 of D per thread ----
  const f32x4* frow = f4 + ((size_t)b * S + s0) * 512 + tid;
  f32x4 acc = {0.f, 0.f, 0.f, 0.f};
#pragma unroll 8
  for (int i = 0; i < spc; ++i) {
    const float w = wlds[i];
    f32x4 v = nt_load4(frow + (size_t)i * 512);
    acc.x += w * v.x;
    acc.y += w * v.y;
    acc.z += w * v.z;
    acc.w += w * v.w;
  }
  po[(size_t)bx * 512 + tid] = acc;
}

// ---------------- K3: merge partials with flash rescale ----------------
// 256 blocks: (b = bx>>2, q = bx&3); thread owns f32x2 index q*256+tid of
// b's 1024. out[b,:] = sum_c e^{m_c-M} o_c / (sum_c l_c e^{m_c-M}).
__global__ __launch_bounds__(256) void k_merge(
    const f32x2* __restrict__ po2, const float2* __restrict__ meta,
    f32x2* __restrict__ out2, int sc) {
  const int bx = blockIdx.x;
  const int b = bx >> 2, q = bx & 3;
  const int tid = threadIdx.x;
  float M = -INFINITY;
  for (int c = 0; c < sc; ++c) M = fmaxf(M, meta[b * sc + c].x);
  float L = 0.f;
  for (int c = 0; c < sc; ++c) {
    float2 mc = meta[b * sc + c];
    L += mc.y * __expf(mc.x - M);
  }
  const float invL = 1.f / L;
  const int off = q * 256 + tid;  // f32x2 index within b's 1024
  f32x2 acc = {0.f, 0.f};
  for (int c = 0; c < sc; ++c) {
    const float w = __expf(meta[b * sc + c].x - M) * invL;
    f32x2 v = po2[((size_t)(b * sc + c)) * 1024 + off];
    acc.x += w * v.x;
    acc.y += w * v.y;
  }
  out2[(size_t)b * 1024 + off] = acc;
}

extern "C" void kernel_launch(void* const* d_in, const int* in_sizes, int n_in,
                              void* d_out, int out_size, void* d_ws,
                              size_t ws_size, hipStream_t stream) {
  const float* h = (const float*)d_in[0];
  const float* att_feats = (const float*)d_in[1];
  const float* p_att = (const float*)d_in[2];
  const float* W = (const float*)d_in[3];
  const float* bh = (const float*)d_in[4];
  const float* wa = (const float*)d_in[5];
  // d_in[6] = b_alpha (cancels in softmax)
  float* out = (float*)d_out;
  float* ws = (float*)d_ws;

  float* att_h = ws;                     // 32768 floats
  float2* meta = (float2*)(ws + 32768);  // pad 4096 floats
  float* po = ws + 32768 + 4096;         // B*sc*2048 floats (16B-aligned)

  int sc = 8;  // 512 blocks: measured-optimal stream shape
  while (sc > 1 &&
         ws_size < (32768ull + 4096ull + (size_t)B * sc * D) * 4ull)
    sc >>= 1;
  const int spc = S / sc;

  k_h2att<<<(B / 4) * (H / 4) / 4, 256, 0, stream>>>(
      (const f32x4*)h, (const f32x4*)W, bh, att_h);
  k_fused<<<B * sc, 512, 0, stream>>>(
      (const f32x4*)p_att, (const f32x4*)att_feats, (const f32x4*)att_h,
      (const f32x4*)wa, (f32x4*)po, meta, sc, spc);
  k_merge<<<B * 4, 256, 0, stream>>>((const f32x2*)po, meta, (f32x2*)out, sc);
}

// Round 12
// 126.258 us; speedup vs baseline: 1.4188x; 1.0192x over previous
//
#include <hip/hip_runtime.h>
#include <hip/hip_bf16.h>

// Problem: B=64, ATT_SIZE(S)=1024, RNN_SIZE(D)=2048, ATT_HID(H)=512
// att_h = h @ W^T + b            [64, 512]
// scores= tanh(p_att + att_h) @ w_alpha   [64, 1024]  (b_alpha cancels in softmax)
// weight= softmax(scores, s)     [64, 1024]
// out   = weight @ att_feats     [64, 2048]
//
// FINAL (champion, r7 config): K1 h2att -> K2 fused at sc=8 (512 blocks x
// 256 thr = 2 blk/CU, 8 waves/CU; measured-optimal across the full sweep:
// streams {256,512,1024,2048}blk -> {132,126.8,~135,146}us; waves/CU
// {8,16} -> {126.8,128.7}; nt loads required (+19us without); flash
// chunk-softmax in-kernel) -> K3 merge (rescale).
// r9 lesson: NO cross-XCD atomic merge inside the streaming kernel (+52us).
// Effective read BW ~5.5-5.6 TB/s = ~88% of 6.3 TB/s copy ceiling.

#define B 64
#define S 1024
#define D 2048
#define H 512

typedef float f32x4 __attribute__((ext_vector_type(4)));
typedef float f32x2 __attribute__((ext_vector_type(2)));

__device__ __forceinline__ f32x4 nt_load4(const f32x4* p) {
  return __builtin_nontemporal_load(p);
}

// fast tanh: 1 - 2/(e^{2x}+1). Safe at +/-inf (e=inf -> 1; e=0 -> -1).
__device__ __forceinline__ float fast_tanh(float x) {
  float e = __expf(2.f * x);
  return 1.f - 2.f * __builtin_amdgcn_rcpf(e + 1.f);
}

// ---------------- K1: att_h = h @ W^T + bias ----------------
// Wave computes a 4b x 4j tile. 512 blocks x 256 threads. (~4.5 us)
__global__ __launch_bounds__(256) void k_h2att(
    const f32x4* __restrict__ h4, const f32x4* __restrict__ W4,
    const float* __restrict__ bias, float* __restrict__ att_h) {
  const int tid = threadIdx.x, lane = tid & 63, wave = tid >> 6;
  const int tile = blockIdx.x * 4 + wave;  // [0, 2048)
  const int b0 = (tile >> 7) << 2;         // [0, 64) step 4
  const int j0 = (tile & 127) << 2;        // [0, 512) step 4
  float acc[4][4] = {};
#pragma unroll
  for (int i = 0; i < 8; ++i) {
    const int idx = lane + i * 64;  // [0, 512) f32x4 within a 2048-f row
    f32x4 hv[4], wv[4];
#pragma unroll
    for (int x = 0; x < 4; ++x) hv[x] = h4[(size_t)(b0 + x) * 512 + idx];
#pragma unroll
    for (int x = 0; x < 4; ++x) wv[x] = W4[(size_t)(j0 + x) * 512 + idx];
#pragma unroll
    for (int bb = 0; bb < 4; ++bb)
#pragma unroll
      for (int jj = 0; jj < 4; ++jj)
        acc[bb][jj] += hv[bb].x * wv[jj].x + hv[bb].y * wv[jj].y +
                       hv[bb].z * wv[jj].z + hv[bb].w * wv[jj].w;
  }
#pragma unroll
  for (int bb = 0; bb < 4; ++bb)
#pragma unroll
    for (int jj = 0; jj < 4; ++jj) {
      float a = acc[bb][jj];
#pragma unroll
      for (int off = 32; off; off >>= 1) a += __shfl_xor(a, off, 64);
      if (lane == bb * 4 + jj)
        att_h[(b0 + bb) * H + j0 + jj] = a + bias[j0 + jj];
    }
}

// ---------------- K2: fused scores + chunk softmax + partial wsum -------
// grid = B*sc = 512 blocks (2/CU); bx -> (b = bx/sc, c = bx%sc), rows
// [c*spc, c*spc+spc), spc=128. Phase 1: 4 score rows per wave-iteration
// (8 indep nt loads in flight) -> slds. Phase 2: chunk-local max m_c,
// e_i = exp(s_i - m_c) -> wlds; meta[bx] = (m_c, l_c). Phase 3: full-D
// partial weighted sum over a contiguous 1 MB att_feats region.
__global__ __launch_bounds__(256) void k_fused(
    const f32x4* __restrict__ p4, const f32x4* __restrict__ f4,
    const f32x4* __restrict__ ah4, const f32x4* __restrict__ wa4,
    f32x4* __restrict__ po, float2* __restrict__ meta, int sc, int spc) {
  __shared__ float slds[S];
  __shared__ float wlds[S];
  __shared__ float redm[4], redl[4];
  const int tid = threadIdx.x, lane = tid & 63, wave = tid >> 6;
  const int bx = blockIdx.x;
  const int b = bx / sc, c = bx - b * sc;
  const int s0 = c * spc;

  // ---- phase 1: scores for this chunk ----
  const f32x4* pbase = p4 + ((size_t)b * S + s0) * 128;
  const f32x4 av0 = ah4[b * 128 + lane], av1 = ah4[b * 128 + 64 + lane];
  const f32x4 wv0 = wa4[lane], wv1 = wa4[64 + lane];
  const int rpw = spc >> 2;    // rows per wave (32 at sc=8)
  const int iters = rpw >> 2;  // 4-row groups per wave
  for (int it = 0; it < iters; ++it) {
    const int sl0 = wave * rpw + it * 4;
    float acc[4];
#pragma unroll
    for (int r = 0; r < 4; ++r) {
      const f32x4* p = pbase + (size_t)(sl0 + r) * 128;
      f32x4 p0 = nt_load4(p + lane), p1 = nt_load4(p + 64 + lane);
      acc[r] = fast_tanh(p0.x + av0.x) * wv0.x +
               fast_tanh(p0.y + av0.y) * wv0.y +
               fast_tanh(p0.z + av0.z) * wv0.z +
               fast_tanh(p0.w + av0.w) * wv0.w +
               fast_tanh(p1.x + av1.x) * wv1.x +
               fast_tanh(p1.y + av1.y) * wv1.y +
               fast_tanh(p1.z + av1.z) * wv1.z +
               fast_tanh(p1.w + av1.w) * wv1.w;
    }
#pragma unroll
    for (int r = 0; r < 4; ++r)
#pragma unroll
      for (int off = 32; off; off >>= 1) acc[r] += __shfl_xor(acc[r], off, 64);
    if (lane == 0) {
      f32x4 o = {acc[0], acc[1], acc[2], acc[3]};
      ((f32x4*)slds)[sl0 >> 2] = o;
    }
  }
  __syncthreads();

  // ---- phase 2: chunk-local softmax weights ----
  float m = -INFINITY;
  for (int i = tid; i < spc; i += 256) m = fmaxf(m, slds[i]);
#pragma unroll
  for (int off = 32; off; off >>= 1) m = fmaxf(m, __shfl_xor(m, off, 64));
  if (lane == 0) redm[wave] = m;
  __syncthreads();
  const float M = fmaxf(fmaxf(redm[0], redm[1]), fmaxf(redm[2], redm[3]));
  float l = 0.f;
  for (int i = tid; i < spc; i += 256) {
    float e = __expf(slds[i] - M);
    wlds[i] = e;
    l += e;
  }
#pragma unroll
  for (int off = 32; off; off >>= 1) l += __shfl_xor(l, off, 64);
  if (lane == 0) redl[wave] = l;
  __syncthreads();
  if (tid == 0)
    meta[bx] = make_float2(M, redl[0] + redl[1] + redl[2] + redl[3]);

  // ---- phase 3: partial weighted sum over this chunk, full D ----
  const f32x4* frow = f4 + ((size_t)b * S + s0) * 512 + tid;
  f32x4 acc0 = {0.f, 0.f, 0.f, 0.f}, acc1 = {0.f, 0.f, 0.f, 0.f};
#pragma unroll 8
  for (int i = 0; i < spc; ++i) {
    const float w = wlds[i];
    f32x4 v0 = nt_load4(frow + (size_t)i * 512);
    f32x4 v1 = nt_load4(frow + (size_t)i * 512 + 256);
    acc0.x += w * v0.x;
    acc0.y += w * v0.y;
    acc0.z += w * v0.z;
    acc0.w += w * v0.w;
    acc1.x += w * v1.x;
    acc1.y += w * v1.y;
    acc1.z += w * v1.z;
    acc1.w += w * v1.w;
  }
  po[(size_t)bx * 512 + tid] = acc0;
  po[(size_t)bx * 512 + tid + 256] = acc1;
}

// ---------------- K3: merge partials with flash rescale ----------------
// 256 blocks: (b = bx>>2, q = bx&3); thread owns f32x2 index q*256+tid of
// b's 1024. out[b,:] = sum_c e^{m_c-M} o_c / (sum_c l_c e^{m_c-M}).
__global__ __launch_bounds__(256) void k_merge(
    const f32x2* __restrict__ po2, const float2* __restrict__ meta,
    f32x2* __restrict__ out2, int sc) {
  const int bx = blockIdx.x;
  const int b = bx >> 2, q = bx & 3;
  const int tid = threadIdx.x;
  float M = -INFINITY;
  for (int c = 0; c < sc; ++c) M = fmaxf(M, meta[b * sc + c].x);
  float L = 0.f;
  for (int c = 0; c < sc; ++c) {
    float2 mc = meta[b * sc + c];
    L += mc.y * __expf(mc.x - M);
  }
  const float invL = 1.f / L;
  const int off = q * 256 + tid;  // f32x2 index within b's 1024
  f32x2 acc = {0.f, 0.f};
  for (int c = 0; c < sc; ++c) {
    const float w = __expf(meta[b * sc + c].x - M) * invL;
    f32x2 v = po2[((size_t)(b * sc + c)) * 1024 + off];
    acc.x += w * v.x;
    acc.y += w * v.y;
  }
  out2[(size_t)b * 1024 + off] = acc;
}

extern "C" void kernel_launch(void* const* d_in, const int* in_sizes, int n_in,
                              void* d_out, int out_size, void* d_ws,
                              size_t ws_size, hipStream_t stream) {
  const float* h = (const float*)d_in[0];
  const float* att_feats = (const float*)d_in[1];
  const float* p_att = (const float*)d_in[2];
  const float* W = (const float*)d_in[3];
  const float* bh = (const float*)d_in[4];
  const float* wa = (const float*)d_in[5];
  // d_in[6] = b_alpha (cancels in softmax)
  float* out = (float*)d_out;
  float* ws = (float*)d_ws;

  float* att_h = ws;                     // 32768 floats
  float2* meta = (float2*)(ws + 32768);  // pad 4096 floats
  float* po = ws + 32768 + 4096;         // B*sc*2048 floats (16B-aligned)

  int sc = 8;  // 512 blocks = 2/CU: measured-optimal stream shape
  while (sc > 1 &&
         ws_size < (32768ull + 4096ull + (size_t)B * sc * D) * 4ull)
    sc >>= 1;
  const int spc = S / sc;

  k_h2att<<<(B / 4) * (H / 4) / 4, 256, 0, stream>>>(
      (const f32x4*)h, (const f32x4*)W, bh, att_h);
  k_fused<<<B * sc, 256, 0, stream>>>(
      (const f32x4*)p_att, (const f32x4*)att_feats, (const f32x4*)att_h,
      (const f32x4*)wa, (f32x4*)po, meta, sc, spc);
  k_merge<<<B * 4, 256, 0, stream>>>((const f32x2*)po, meta, (f32x2*)out, sc);
}